// Round 1
// baseline (176.148 us; speedup 1.0000x reference)
//
#include <hip/hip_runtime.h>
#include <hip/hip_bf16.h>

namespace {

constexpr int kB = 2, kS = 512, kE = 1024, kH = 16, kD = 64;
constexpr int kM = kB * kS;   // 1024 rows in the 1024^3 GEMMs
constexpr int kBH = kB * kH;  // 32 (b,h) pairs

typedef short bf16x8 __attribute__((ext_vector_type(8)));
typedef float f32x4 __attribute__((ext_vector_type(4)));
typedef unsigned short u16x8 __attribute__((ext_vector_type(8)));

__device__ __forceinline__ unsigned short f2bf(float f) {
  __hip_bfloat16 h = __float2bfloat16(f);
  unsigned short u;
  __builtin_memcpy(&u, &h, 2);
  return u;
}
__device__ __forceinline__ float bf2f(unsigned short u) {
  unsigned int x = (unsigned int)u << 16;
  float f;
  __builtin_memcpy(&f, &x, 4);
  return f;
}

// ---------------- f32 -> bf16 conversion ----------------
__global__ void cvt_kernel(const float* __restrict__ src,
                           unsigned short* __restrict__ dst, int n) {
  int i = (blockIdx.x * blockDim.x + threadIdx.x) * 4;
  if (i >= n) return;
  float4 v = *reinterpret_cast<const float4*>(src + i);
  ushort4 o;
  o.x = f2bf(v.x); o.y = f2bf(v.y); o.z = f2bf(v.z); o.w = f2bf(v.w);
  *reinterpret_cast<ushort4*>(dst + i) = o;
}

// ---------------- generic 32x32 MFMA tile: C = A * B^T ----------------
// A: [M x K] row-major (lda), Bm: [N x K] row-major (ldb). Both operands load
// identical K-contiguous 16B fragments, so intra-fragment K-order cancels.
__device__ __forceinline__ void mfma_tile_32x32(
    const unsigned short* __restrict__ A, int lda,
    const unsigned short* __restrict__ Bm, int ldb,
    int row0, int col0, int K, f32x4 acc[2][2]) {
  const int lane = threadIdx.x & 63;
  const int r = lane & 15;
  const int ko = (lane >> 4) * 8;
  const unsigned short* a0 = A + (size_t)(row0 + r) * lda + ko;
  const unsigned short* a1 = a0 + 16 * (size_t)lda;
  const unsigned short* b0 = Bm + (size_t)(col0 + r) * ldb + ko;
  const unsigned short* b1 = b0 + 16 * (size_t)ldb;
  for (int kk = 0; kk < K; kk += 32) {
    bf16x8 af0 = *reinterpret_cast<const bf16x8*>(a0 + kk);
    bf16x8 af1 = *reinterpret_cast<const bf16x8*>(a1 + kk);
    bf16x8 bg0 = *reinterpret_cast<const bf16x8*>(b0 + kk);
    bf16x8 bg1 = *reinterpret_cast<const bf16x8*>(b1 + kk);
    acc[0][0] = __builtin_amdgcn_mfma_f32_16x16x32_bf16(af0, bg0, acc[0][0], 0, 0, 0);
    acc[0][1] = __builtin_amdgcn_mfma_f32_16x16x32_bf16(af0, bg1, acc[0][1], 0, 0, 0);
    acc[1][0] = __builtin_amdgcn_mfma_f32_16x16x32_bf16(af1, bg0, acc[1][0], 0, 0, 0);
    acc[1][1] = __builtin_amdgcn_mfma_f32_16x16x32_bf16(af1, bg1, acc[1][1], 0, 0, 0);
  }
}

// ---------------- projections: qh/kh [B,H,S,D], vh^T [B,H,D,S] ----------------
__global__ void proj_kernel(const unsigned short* __restrict__ qb,
                            const unsigned short* __restrict__ kb,
                            const unsigned short* __restrict__ vb,
                            const unsigned short* __restrict__ Wq,
                            const unsigned short* __restrict__ Wk,
                            const unsigned short* __restrict__ Wv,
                            unsigned short* __restrict__ qh,
                            unsigned short* __restrict__ kh,
                            unsigned short* __restrict__ vhT) {
  const int which = blockIdx.z;
  const unsigned short* A = which == 0 ? qb : (which == 1 ? kb : vb);
  const unsigned short* W = which == 0 ? Wq : (which == 1 ? Wk : Wv);
  const int row0 = blockIdx.y * 32, col0 = blockIdx.x * 32;
  f32x4 acc[2][2] = {};
  mfma_tile_32x32(A, kE, W, kE, row0, col0, kE, acc);
  const int lane = threadIdx.x & 63;
#pragma unroll
  for (int ri = 0; ri < 2; ++ri)
#pragma unroll
    for (int ci = 0; ci < 2; ++ci)
#pragma unroll
      for (int r = 0; r < 4; ++r) {
        int i = row0 + 16 * ri + 4 * (lane >> 4) + r;  // b*512+s
        int j = col0 + 16 * ci + (lane & 15);          // h*64+d
        int b = i >> 9, s = i & 511, h = j >> 6, d = j & 63;
        unsigned short val = f2bf(acc[ri][ci][r]);
        if (which == 2)
          vhT[(((size_t)(b * kH + h) * kD) + d) * kS + s] = val;
        else if (which == 1)
          kh[(((size_t)(b * kH + h) * kS) + s) * kD + d] = val;
        else
          qh[(((size_t)(b * kH + h) * kS) + s) * kD + d] = val;
      }
}

// ---------------- qp[b,h,s,f] = sum_e qh[b,h,s,e] * p[b,s,h,e,f] ----------------
// One block per (b,s): 256 threads = 16 h-groups x 16 lanes, each lane 4 f's.
__global__ void qp_kernel(const float* __restrict__ p,
                          const unsigned short* __restrict__ qh,
                          unsigned short* __restrict__ qp) {
  __shared__ float qsh[kH][kD];
  const int bs = blockIdx.x;  // b*512+s
  const int b = bs >> 9, s = bs & 511;
  const int t = threadIdx.x;
  {
    int h = t >> 4, d4 = (t & 15) * 4;
    const unsigned short* qr =
        qh + (((size_t)(b * kH + h) * kS) + s) * kD + d4;
    ushort4 u = *reinterpret_cast<const ushort4*>(qr);
    qsh[h][d4 + 0] = bf2f(u.x);
    qsh[h][d4 + 1] = bf2f(u.y);
    qsh[h][d4 + 2] = bf2f(u.z);
    qsh[h][d4 + 3] = bf2f(u.w);
  }
  __syncthreads();
  const int h = t >> 4, fi = t & 15;
  const float4* p4 =
      reinterpret_cast<const float4*>(p + ((size_t)(bs * kH + h) << 12));
  float4 acc = {0.f, 0.f, 0.f, 0.f};
#pragma unroll 4
  for (int e = 0; e < kD; ++e) {
    float4 pv = p4[e * 16 + fi];
    float qv = qsh[h][e];
    acc.x += qv * pv.x;
    acc.y += qv * pv.y;
    acc.z += qv * pv.z;
    acc.w += qv * pv.w;
  }
  ushort4 o;
  o.x = f2bf(acc.x); o.y = f2bf(acc.y); o.z = f2bf(acc.z); o.w = f2bf(acc.w);
  *reinterpret_cast<ushort4*>(
      qp + (((size_t)(b * kH + h) * kS) + s) * kD + fi * 4) = o;
}

// ---------------- scores = qp . kh^T / 8 + mask ----------------
__global__ void scores_kernel(const unsigned short* __restrict__ qp,
                              const unsigned short* __restrict__ kh,
                              const float* __restrict__ mask,
                              float* __restrict__ scores) {
  const int bh = blockIdx.z;
  const int row0 = blockIdx.y * 32, col0 = blockIdx.x * 32;
  const unsigned short* A = qp + (size_t)bh * kS * kD;
  const unsigned short* Bm = kh + (size_t)bh * kS * kD;
  float* C = scores + (size_t)bh * kS * kS;
  f32x4 acc[2][2] = {};
  if (col0 <= row0 + 31)  // skip fully-masked tiles (above the diagonal)
    mfma_tile_32x32(A, kD, Bm, kD, row0, col0, kD, acc);
  const int lane = threadIdx.x & 63;
#pragma unroll
  for (int ri = 0; ri < 2; ++ri)
#pragma unroll
    for (int ci = 0; ci < 2; ++ci)
#pragma unroll
      for (int r = 0; r < 4; ++r) {
        int i = row0 + 16 * ri + 4 * (lane >> 4) + r;
        int j = col0 + 16 * ci + (lane & 15);
        C[(size_t)i * kS + j] = acc[ri][ci][r] * 0.125f + mask[(size_t)i * kS + j];
      }
}

// ---------------- row softmax (one wave per row), write bf16 w ----------------
__global__ void softmax_kernel(const float* __restrict__ scores,
                               unsigned short* __restrict__ w) {
  const int row = blockIdx.x * 4 + (threadIdx.x >> 6);  // bh*512 + s
  const int lane = threadIdx.x & 63;
  const float* src = scores + (size_t)row * kS + lane * 8;
  float4 v0 = *reinterpret_cast<const float4*>(src);
  float4 v1 = *reinterpret_cast<const float4*>(src + 4);
  float vals[8] = {v0.x, v0.y, v0.z, v0.w, v1.x, v1.y, v1.z, v1.w};
  float m = vals[0];
#pragma unroll
  for (int i = 1; i < 8; ++i) m = fmaxf(m, vals[i]);
#pragma unroll
  for (int off = 32; off; off >>= 1) m = fmaxf(m, __shfl_xor(m, off));
  float e[8];
  float sum = 0.f;
#pragma unroll
  for (int i = 0; i < 8; ++i) {
    e[i] = __expf(vals[i] - m);
    sum += e[i];
  }
#pragma unroll
  for (int off = 32; off; off >>= 1) sum += __shfl_xor(sum, off);
  const float inv = 1.0f / sum;
  u16x8 o;
#pragma unroll
  for (int i = 0; i < 8; ++i) o[i] = f2bf(e[i] * inv);
  *reinterpret_cast<u16x8*>(w + (size_t)row * kS + lane * 8) = o;
}

// ---------------- att[b,s,h*64+d] = sum_t w[s,t] * vh[t,d] ----------------
__global__ void att_kernel(const unsigned short* __restrict__ w,
                           const unsigned short* __restrict__ vhT,
                           unsigned short* __restrict__ att) {
  const int bh = blockIdx.z;
  const int b = bh >> 4, h = bh & 15;
  const int row0 = blockIdx.y * 32, col0 = blockIdx.x * 32;
  const unsigned short* A = w + (size_t)bh * kS * kS;
  const unsigned short* Bm = vhT + (size_t)bh * kD * kS;
  f32x4 acc[2][2] = {};
  // causal: w[s,t]==0 for t>s, so K can stop at row0+32
  mfma_tile_32x32(A, kS, Bm, kS, row0, col0, row0 + 32, acc);
  const int lane = threadIdx.x & 63;
#pragma unroll
  for (int ri = 0; ri < 2; ++ri)
#pragma unroll
    for (int ci = 0; ci < 2; ++ci)
#pragma unroll
      for (int r = 0; r < 4; ++r) {
        int s = row0 + 16 * ri + 4 * (lane >> 4) + r;
        int d = col0 + 16 * ci + (lane & 15);
        att[((size_t)(b * kS + s) * kE) + h * kD + d] = f2bf(acc[ri][ci][r]);
      }
}

// ---------------- out = att @ Wo^T (f32 output) ----------------
__global__ void out_kernel(const unsigned short* __restrict__ att,
                           const unsigned short* __restrict__ Wo,
                           float* __restrict__ out) {
  const int row0 = blockIdx.y * 32, col0 = blockIdx.x * 32;
  f32x4 acc[2][2] = {};
  mfma_tile_32x32(att, kE, Wo, kE, row0, col0, kE, acc);
  const int lane = threadIdx.x & 63;
#pragma unroll
  for (int ri = 0; ri < 2; ++ri)
#pragma unroll
    for (int ci = 0; ci < 2; ++ci)
#pragma unroll
      for (int r = 0; r < 4; ++r) {
        int i = row0 + 16 * ri + 4 * (lane >> 4) + r;
        int j = col0 + 16 * ci + (lane & 15);
        out[(size_t)i * kE + j] = acc[ri][ci][r];
      }
}

}  // namespace

extern "C" void kernel_launch(void* const* d_in, const int* in_sizes, int n_in,
                              void* d_out, int out_size, void* d_ws,
                              size_t ws_size, hipStream_t stream) {
  const float* q = (const float*)d_in[0];
  const float* k = (const float*)d_in[1];
  const float* v = (const float*)d_in[2];
  const float* p = (const float*)d_in[3];
  const float* mask = (const float*)d_in[4];
  const float* Wq = (const float*)d_in[5];
  const float* Wk = (const float*)d_in[6];
  const float* Wv = (const float*)d_in[7];
  const float* Wo = (const float*)d_in[8];
  float* out = (float*)d_out;

  char* ws = (char*)d_ws;
  size_t off = 0;
  auto alloc = [&](size_t bytes) {
    void* ptr = ws + off;
    off += (bytes + 255) & ~(size_t)255;
    return ptr;
  };
  const size_t nME = (size_t)kM * kE;  // 1,048,576
  unsigned short* qb = (unsigned short*)alloc(nME * 2);
  unsigned short* kb = (unsigned short*)alloc(nME * 2);
  unsigned short* vb = (unsigned short*)alloc(nME * 2);
  unsigned short* Wqb = (unsigned short*)alloc(nME * 2);
  unsigned short* Wkb = (unsigned short*)alloc(nME * 2);
  unsigned short* Wvb = (unsigned short*)alloc(nME * 2);
  unsigned short* Wob = (unsigned short*)alloc(nME * 2);
  unsigned short* qhB = (unsigned short*)alloc(nME * 2);
  unsigned short* khB = (unsigned short*)alloc(nME * 2);
  unsigned short* vhTB = (unsigned short*)alloc(nME * 2);
  unsigned short* qpB = (unsigned short*)alloc(nME * 2);
  float* scoresB = (float*)alloc((size_t)kBH * kS * kS * 4);  // 32 MB
  unsigned short* wB = (unsigned short*)alloc((size_t)kBH * kS * kS * 2);  // 16 MB
  unsigned short* attB = (unsigned short*)alloc(nME * 2);

  const int n = (int)nME;
  const int cvtBlocks = n / (256 * 4);
  cvt_kernel<<<cvtBlocks, 256, 0, stream>>>(q, qb, n);
  cvt_kernel<<<cvtBlocks, 256, 0, stream>>>(k, kb, n);
  cvt_kernel<<<cvtBlocks, 256, 0, stream>>>(v, vb, n);
  cvt_kernel<<<cvtBlocks, 256, 0, stream>>>(Wq, Wqb, n);
  cvt_kernel<<<cvtBlocks, 256, 0, stream>>>(Wk, Wkb, n);
  cvt_kernel<<<cvtBlocks, 256, 0, stream>>>(Wv, Wvb, n);
  cvt_kernel<<<cvtBlocks, 256, 0, stream>>>(Wo, Wob, n);

  proj_kernel<<<dim3(kE / 32, kM / 32, 3), 64, 0, stream>>>(
      qb, kb, vb, Wqb, Wkb, Wvb, qhB, khB, vhTB);

  qp_kernel<<<kB * kS, 256, 0, stream>>>(p, qhB, qpB);

  scores_kernel<<<dim3(kS / 32, kS / 32, kBH), 64, 0, stream>>>(
      qpB, khB, mask, scoresB);

  softmax_kernel<<<(kBH * kS) / 4, 256, 0, stream>>>(scoresB, wB);

  att_kernel<<<dim3(kD / 32, kS / 32, kBH), 64, 0, stream>>>(wB, vhTB, attB);

  out_kernel<<<dim3(kE / 32, kM / 32, 1), 64, 0, stream>>>(attB, Wob, out);
}

// Round 2
// 145.999 us; speedup vs baseline: 1.2065x; 1.2065x over previous
//
#include <hip/hip_runtime.h>
#include <hip/hip_bf16.h>

namespace {

constexpr int kB = 2, kS = 512, kE = 1024, kH = 16, kD = 64;
constexpr int kM = kB * kS;   // 1024 rows in the 1024^3 GEMMs
constexpr int kBH = kB * kH;  // 32 (b,h) pairs
constexpr int kSP = 524;      // padded LDS score row stride (f32): 12 mod 32 -> <=2-way banks

typedef short bf16x8 __attribute__((ext_vector_type(8)));
typedef float f32x4 __attribute__((ext_vector_type(4)));

__device__ __forceinline__ unsigned short f2bf(float f) {
  __hip_bfloat16 h = __float2bfloat16(f);
  unsigned short u;
  __builtin_memcpy(&u, &h, 2);
  return u;
}
__device__ __forceinline__ float bf2f(unsigned short u) {
  unsigned int x = (unsigned int)u << 16;
  float f;
  __builtin_memcpy(&f, &x, 4);
  return f;
}

// ---------------- f32 -> bf16 conversion, all 7 tensors in one launch --------
// dst buffers are 7 consecutive 2MB regions starting at dstBase.
__global__ void cvt7_kernel(const float* __restrict__ s0, const float* __restrict__ s1,
                            const float* __restrict__ s2, const float* __restrict__ s3,
                            const float* __restrict__ s4, const float* __restrict__ s5,
                            const float* __restrict__ s6,
                            unsigned short* __restrict__ dstBase) {
  const float* srcs[7] = {s0, s1, s2, s3, s4, s5, s6};
  const float* src = srcs[blockIdx.y];
  unsigned short* dst = dstBase + (size_t)blockIdx.y * (kM * kE);
  int i = (blockIdx.x * blockDim.x + threadIdx.x) * 4;
  float4 v = *reinterpret_cast<const float4*>(src + i);
  ushort4 o;
  o.x = f2bf(v.x); o.y = f2bf(v.y); o.z = f2bf(v.z); o.w = f2bf(v.w);
  *reinterpret_cast<ushort4*>(dst + i) = o;
}

// ---------------- generic 32x32 MFMA tile: C = A * B^T ----------------
// A: [M x K] row-major (lda), Bm: [N x K] row-major (ldb). Both operands load
// identical K-contiguous 16B fragments, so intra-fragment K-order cancels.
__device__ __forceinline__ void mfma_tile_32x32(
    const unsigned short* __restrict__ A, int lda,
    const unsigned short* __restrict__ Bm, int ldb,
    int row0, int col0, int K, f32x4 acc[2][2]) {
  const int lane = threadIdx.x & 63;
  const int r = lane & 15;
  const int ko = (lane >> 4) * 8;
  const unsigned short* a0 = A + (size_t)(row0 + r) * lda + ko;
  const unsigned short* a1 = a0 + 16 * (size_t)lda;
  const unsigned short* b0 = Bm + (size_t)(col0 + r) * ldb + ko;
  const unsigned short* b1 = b0 + 16 * (size_t)ldb;
  for (int kk = 0; kk < K; kk += 32) {
    bf16x8 af0 = *reinterpret_cast<const bf16x8*>(a0 + kk);
    bf16x8 af1 = *reinterpret_cast<const bf16x8*>(a1 + kk);
    bf16x8 bg0 = *reinterpret_cast<const bf16x8*>(b0 + kk);
    bf16x8 bg1 = *reinterpret_cast<const bf16x8*>(b1 + kk);
    acc[0][0] = __builtin_amdgcn_mfma_f32_16x16x32_bf16(af0, bg0, acc[0][0], 0, 0, 0);
    acc[0][1] = __builtin_amdgcn_mfma_f32_16x16x32_bf16(af0, bg1, acc[0][1], 0, 0, 0);
    acc[1][0] = __builtin_amdgcn_mfma_f32_16x16x32_bf16(af1, bg0, acc[1][0], 0, 0, 0);
    acc[1][1] = __builtin_amdgcn_mfma_f32_16x16x32_bf16(af1, bg1, acc[1][1], 0, 0, 0);
  }
}

// ---------------- projections: qh/kh [B,H,S,D], vh^T [B,H,D,S] ----------------
__global__ void proj_kernel(const unsigned short* __restrict__ qb,
                            const unsigned short* __restrict__ kb,
                            const unsigned short* __restrict__ vb,
                            const unsigned short* __restrict__ Wq,
                            const unsigned short* __restrict__ Wk,
                            const unsigned short* __restrict__ Wv,
                            unsigned short* __restrict__ qh,
                            unsigned short* __restrict__ kh,
                            unsigned short* __restrict__ vhT) {
  const int which = blockIdx.z;
  const unsigned short* A = which == 0 ? qb : (which == 1 ? kb : vb);
  const unsigned short* W = which == 0 ? Wq : (which == 1 ? Wk : Wv);
  const int row0 = blockIdx.y * 32, col0 = blockIdx.x * 32;
  f32x4 acc[2][2] = {};
  mfma_tile_32x32(A, kE, W, kE, row0, col0, kE, acc);
  const int lane = threadIdx.x & 63;
#pragma unroll
  for (int ri = 0; ri < 2; ++ri)
#pragma unroll
    for (int ci = 0; ci < 2; ++ci)
#pragma unroll
      for (int r = 0; r < 4; ++r) {
        int i = row0 + 16 * ri + 4 * (lane >> 4) + r;  // b*512+s
        int j = col0 + 16 * ci + (lane & 15);          // h*64+d
        int b = i >> 9, s = i & 511, h = j >> 6, d = j & 63;
        unsigned short val = f2bf(acc[ri][ci][r]);
        if (which == 2)
          vhT[(((size_t)(b * kH + h) * kD) + d) * kS + s] = val;
        else if (which == 1)
          kh[(((size_t)(b * kH + h) * kS) + s) * kD + d] = val;
        else
          qh[(((size_t)(b * kH + h) * kS) + s) * kD + d] = val;
      }
}

// ---------------- qp[b,h,s,f] = sum_e qh[b,h,s,e] * p[b,s,h,e,f] ----------------
__global__ void qp_kernel(const float* __restrict__ p,
                          const unsigned short* __restrict__ qh,
                          unsigned short* __restrict__ qp) {
  __shared__ float qsh[kH][kD];
  const int bs = blockIdx.x;  // b*512+s
  const int b = bs >> 9, s = bs & 511;
  const int t = threadIdx.x;
  {
    int h = t >> 4, d4 = (t & 15) * 4;
    const unsigned short* qr =
        qh + (((size_t)(b * kH + h) * kS) + s) * kD + d4;
    ushort4 u = *reinterpret_cast<const ushort4*>(qr);
    qsh[h][d4 + 0] = bf2f(u.x);
    qsh[h][d4 + 1] = bf2f(u.y);
    qsh[h][d4 + 2] = bf2f(u.z);
    qsh[h][d4 + 3] = bf2f(u.w);
  }
  __syncthreads();
  const int h = t >> 4, fi = t & 15;
  const float4* p4 =
      reinterpret_cast<const float4*>(p + ((size_t)(bs * kH + h) << 12));
  float4 acc = {0.f, 0.f, 0.f, 0.f};
#pragma unroll 4
  for (int e = 0; e < kD; ++e) {
    float4 pv = p4[e * 16 + fi];
    float qv = qsh[h][e];
    acc.x += qv * pv.x;
    acc.y += qv * pv.y;
    acc.z += qv * pv.z;
    acc.w += qv * pv.w;
  }
  ushort4 o;
  o.x = f2bf(acc.x); o.y = f2bf(acc.y); o.z = f2bf(acc.z); o.w = f2bf(acc.w);
  *reinterpret_cast<ushort4*>(
      qp + (((size_t)(b * kH + h) * kS) + s) * kD + fi * 4) = o;
}

// ---------------- fused scores -> softmax -> PV -------------------------------
// One block per (bh, 32-row q-tile). 4 waves.
// Phase 1: waves split score col-tiles (<= diag), MFMA -> LDS f32 (scaled+masked)
// Phase 2: in-LDS row softmax (normalized exp written back in place)
// Phase 3: each wave one 16-wide d-strip; P packed bf16 on the fly; PV MFMA.
__global__ __launch_bounds__(256) void attn_kernel(
    const unsigned short* __restrict__ qp,
    const unsigned short* __restrict__ kh,
    const unsigned short* __restrict__ vhT,
    unsigned short* __restrict__ att) {
  __shared__ float S[32 * kSP];  // ~67 KB
  const int bh = blockIdx.y;
  const int b = bh >> 4, h = bh & 15;
  const int bx = blockIdx.x;
  const int row0 = bx * 32;
  const int ncol = row0 + 32;  // causal: cols [0, ncol) are live
  const int w = threadIdx.x >> 6;
  const int lane = threadIdx.x & 63;
  const int g = lane >> 4, c = lane & 15;

  const unsigned short* Abase = qp + (size_t)bh * kS * kD;
  const unsigned short* Kbase = kh + (size_t)bh * kS * kD;

  // hoisted qp fragments for this block's 32 rows (K = 64 -> 2 k-steps)
  bf16x8 qa[2][2];
#pragma unroll
  for (int ri = 0; ri < 2; ++ri)
#pragma unroll
    for (int kk = 0; kk < 2; ++kk)
      qa[ri][kk] = *reinterpret_cast<const bf16x8*>(
          Abase + (size_t)(row0 + 16 * ri + c) * kD + kk * 32 + g * 8);

  // ---- phase 1: scores ----
  for (int ct = w; ct <= bx; ct += 4) {
    const int col0 = ct * 32;
    const unsigned short* kr0 = Kbase + (size_t)(col0 + c) * kD + g * 8;
    bf16x8 kb00 = *reinterpret_cast<const bf16x8*>(kr0);
    bf16x8 kb01 = *reinterpret_cast<const bf16x8*>(kr0 + 32);
    bf16x8 kb10 = *reinterpret_cast<const bf16x8*>(kr0 + 16 * kD);
    bf16x8 kb11 = *reinterpret_cast<const bf16x8*>(kr0 + 16 * kD + 32);
    f32x4 sacc[2][2] = {};
    sacc[0][0] = __builtin_amdgcn_mfma_f32_16x16x32_bf16(qa[0][0], kb00, sacc[0][0], 0, 0, 0);
    sacc[0][0] = __builtin_amdgcn_mfma_f32_16x16x32_bf16(qa[0][1], kb01, sacc[0][0], 0, 0, 0);
    sacc[0][1] = __builtin_amdgcn_mfma_f32_16x16x32_bf16(qa[0][0], kb10, sacc[0][1], 0, 0, 0);
    sacc[0][1] = __builtin_amdgcn_mfma_f32_16x16x32_bf16(qa[0][1], kb11, sacc[0][1], 0, 0, 0);
    sacc[1][0] = __builtin_amdgcn_mfma_f32_16x16x32_bf16(qa[1][0], kb00, sacc[1][0], 0, 0, 0);
    sacc[1][0] = __builtin_amdgcn_mfma_f32_16x16x32_bf16(qa[1][1], kb01, sacc[1][0], 0, 0, 0);
    sacc[1][1] = __builtin_amdgcn_mfma_f32_16x16x32_bf16(qa[1][0], kb10, sacc[1][1], 0, 0, 0);
    sacc[1][1] = __builtin_amdgcn_mfma_f32_16x16x32_bf16(qa[1][1], kb11, sacc[1][1], 0, 0, 0);
#pragma unroll
    for (int ri = 0; ri < 2; ++ri)
#pragma unroll
      for (int ci = 0; ci < 2; ++ci)
#pragma unroll
        for (int r = 0; r < 4; ++r) {
          int il = 16 * ri + 4 * g + r;       // local row
          int jg = col0 + 16 * ci + c;        // global col
          float val = sacc[ri][ci][r] * 0.125f;
          if (jg > row0 + il) val = -1e9f;    // causal mask (inline)
          S[il * kSP + jg] = val;
        }
  }
  __syncthreads();

  // ---- phase 2: softmax, rows w*8 .. w*8+7 ----
#pragma unroll
  for (int rr = 0; rr < 8; ++rr) {
    const int i = w * 8 + rr;
    float v[8];
    float m = -1e30f;
#pragma unroll
    for (int ii = 0; ii < 8; ++ii) {
      int j = lane + 64 * ii;
      v[ii] = (j < ncol) ? S[i * kSP + j] : -1e30f;
      m = fmaxf(m, v[ii]);
    }
#pragma unroll
    for (int off = 32; off; off >>= 1) m = fmaxf(m, __shfl_xor(m, off));
    float e[8], sum = 0.f;
#pragma unroll
    for (int ii = 0; ii < 8; ++ii) {
      e[ii] = __expf(v[ii] - m);  // -1e30 sentinel -> 0
      sum += e[ii];
    }
#pragma unroll
    for (int off = 32; off; off >>= 1) sum += __shfl_xor(sum, off);
    const float inv = 1.0f / sum;
#pragma unroll
    for (int ii = 0; ii < 8; ++ii) S[i * kSP + lane + 64 * ii] = e[ii] * inv;
  }
  __syncthreads();

  // ---- phase 3: PV, wave w handles d in [16w, 16w+16) ----
  const int d0 = w * 16;
  const unsigned short* Vbase = vhT + (size_t)(bh * kD + d0 + c) * kS;
  f32x4 oacc[2] = {};
  const int nk = bx + 1;
  for (int ks = 0; ks < nk; ++ks) {
    const int kb = ks * 32;
    bf16x8 vfrag = *reinterpret_cast<const bf16x8*>(Vbase + kb + g * 8);
#pragma unroll
    for (int ri = 0; ri < 2; ++ri) {
      const float* sp = &S[(16 * ri + c) * kSP + kb + g * 8];
      float4 x0 = *reinterpret_cast<const float4*>(sp);
      float4 x1 = *reinterpret_cast<const float4*>(sp + 4);
      bf16x8 pa;
      pa[0] = (short)f2bf(x0.x); pa[1] = (short)f2bf(x0.y);
      pa[2] = (short)f2bf(x0.z); pa[3] = (short)f2bf(x0.w);
      pa[4] = (short)f2bf(x1.x); pa[5] = (short)f2bf(x1.y);
      pa[6] = (short)f2bf(x1.z); pa[7] = (short)f2bf(x1.w);
      oacc[ri] = __builtin_amdgcn_mfma_f32_16x16x32_bf16(pa, vfrag, oacc[ri], 0, 0, 0);
    }
  }
#pragma unroll
  for (int ri = 0; ri < 2; ++ri)
#pragma unroll
    for (int r = 0; r < 4; ++r) {
      int s = row0 + 16 * ri + 4 * g + r;
      int d = d0 + c;
      att[((size_t)(b * kS + s) * kE) + h * kD + d] = f2bf(oacc[ri][r]);
    }
}

// ---------------- out = att @ Wo^T (f32 output) ----------------
__global__ void out_kernel(const unsigned short* __restrict__ att,
                           const unsigned short* __restrict__ Wo,
                           float* __restrict__ out) {
  const int row0 = blockIdx.y * 32, col0 = blockIdx.x * 32;
  f32x4 acc[2][2] = {};
  mfma_tile_32x32(att, kE, Wo, kE, row0, col0, kE, acc);
  const int lane = threadIdx.x & 63;
#pragma unroll
  for (int ri = 0; ri < 2; ++ri)
#pragma unroll
    for (int ci = 0; ci < 2; ++ci)
#pragma unroll
      for (int r = 0; r < 4; ++r) {
        int i = row0 + 16 * ri + 4 * (lane >> 4) + r;
        int j = col0 + 16 * ci + (lane & 15);
        out[(size_t)i * kE + j] = acc[ri][ci][r];
      }
}

}  // namespace

extern "C" void kernel_launch(void* const* d_in, const int* in_sizes, int n_in,
                              void* d_out, int out_size, void* d_ws,
                              size_t ws_size, hipStream_t stream) {
  const float* q = (const float*)d_in[0];
  const float* k = (const float*)d_in[1];
  const float* v = (const float*)d_in[2];
  const float* p = (const float*)d_in[3];
  const float* Wq = (const float*)d_in[5];
  const float* Wk = (const float*)d_in[6];
  const float* Wv = (const float*)d_in[7];
  const float* Wo = (const float*)d_in[8];
  float* out = (float*)d_out;

  char* ws = (char*)d_ws;
  size_t off = 0;
  auto alloc = [&](size_t bytes) {
    void* ptr = ws + off;
    off += (bytes + 255) & ~(size_t)255;
    return ptr;
  };
  const size_t nME = (size_t)kM * kE;  // 1,048,576
  // NOTE: these 7 must stay consecutive 2MB regions (cvt7 indexes off qb).
  unsigned short* qb = (unsigned short*)alloc(nME * 2);
  unsigned short* kb = (unsigned short*)alloc(nME * 2);
  unsigned short* vb = (unsigned short*)alloc(nME * 2);
  unsigned short* Wqb = (unsigned short*)alloc(nME * 2);
  unsigned short* Wkb = (unsigned short*)alloc(nME * 2);
  unsigned short* Wvb = (unsigned short*)alloc(nME * 2);
  unsigned short* Wob = (unsigned short*)alloc(nME * 2);
  unsigned short* qhB = (unsigned short*)alloc(nME * 2);
  unsigned short* khB = (unsigned short*)alloc(nME * 2);
  unsigned short* vhTB = (unsigned short*)alloc(nME * 2);
  unsigned short* qpB = (unsigned short*)alloc(nME * 2);
  unsigned short* attB = (unsigned short*)alloc(nME * 2);

  cvt7_kernel<<<dim3(kM * kE / (256 * 4), 7), 256, 0, stream>>>(
      q, k, v, Wq, Wk, Wv, Wo, qb);

  proj_kernel<<<dim3(kE / 32, kM / 32, 3), 64, 0, stream>>>(
      qb, kb, vb, Wqb, Wkb, Wvb, qhB, khB, vhTB);

  qp_kernel<<<kB * kS, 256, 0, stream>>>(p, qhB, qpB);

  attn_kernel<<<dim3(kS / 32, kBH), 256, 0, stream>>>(qpB, khB, vhTB, attB);

  out_kernel<<<dim3(kE / 32, kM / 32), 64, 0, stream>>>(attB, Wob, out);
}

// Round 3
// 144.598 us; speedup vs baseline: 1.2182x; 1.0097x over previous
//
#include <hip/hip_runtime.h>
#include <hip/hip_bf16.h>

namespace {

constexpr int kB = 2, kS = 512, kE = 1024, kH = 16, kD = 64;
constexpr int kM = kB * kS;   // 1024 rows in the 1024^3 GEMMs
constexpr int kBH = kB * kH;  // 32 (b,h) pairs
constexpr int kSP = 524;      // padded LDS score row stride (f32)

typedef short bf16x8 __attribute__((ext_vector_type(8)));
typedef float f32x4 __attribute__((ext_vector_type(4)));

__device__ __forceinline__ unsigned short f2bf(float f) {
  __hip_bfloat16 h = __float2bfloat16(f);
  unsigned short u;
  __builtin_memcpy(&u, &h, 2);
  return u;
}
__device__ __forceinline__ float bf2f(unsigned short u) {
  unsigned int x = (unsigned int)u << 16;
  float f;
  __builtin_memcpy(&f, &x, 4);
  return f;
}

// ---------------- f32 -> bf16 conversion, all 7 tensors in one launch --------
__global__ void cvt7_kernel(const float* __restrict__ s0, const float* __restrict__ s1,
                            const float* __restrict__ s2, const float* __restrict__ s3,
                            const float* __restrict__ s4, const float* __restrict__ s5,
                            const float* __restrict__ s6,
                            unsigned short* __restrict__ dstBase) {
  const float* srcs[7] = {s0, s1, s2, s3, s4, s5, s6};
  const float* src = srcs[blockIdx.y];
  unsigned short* dst = dstBase + (size_t)blockIdx.y * (kM * kE);
  int i = (blockIdx.x * blockDim.x + threadIdx.x) * 4;
  float4 v = *reinterpret_cast<const float4*>(src + i);
  ushort4 o;
  o.x = f2bf(v.x); o.y = f2bf(v.y); o.z = f2bf(v.z); o.w = f2bf(v.w);
  *reinterpret_cast<ushort4*>(dst + i) = o;
}

// ---------------- generic 32x32 MFMA tile: C = A * B^T ----------------
// A: [M x K] row-major (lda), Bm: [N x K] row-major (ldb). Both operands load
// identical K-contiguous 16B fragments, so intra-fragment K-order cancels.
__device__ __forceinline__ void mfma_tile_32x32(
    const unsigned short* __restrict__ A, int lda,
    const unsigned short* __restrict__ Bm, int ldb,
    int row0, int col0, int K, f32x4 acc[2][2]) {
  const int lane = threadIdx.x & 63;
  const int r = lane & 15;
  const int ko = (lane >> 4) * 8;
  const unsigned short* a0 = A + (size_t)(row0 + r) * lda + ko;
  const unsigned short* a1 = a0 + 16 * (size_t)lda;
  const unsigned short* b0 = Bm + (size_t)(col0 + r) * ldb + ko;
  const unsigned short* b1 = b0 + 16 * (size_t)ldb;
  for (int kk = 0; kk < K; kk += 32) {
    bf16x8 af0 = *reinterpret_cast<const bf16x8*>(a0 + kk);
    bf16x8 af1 = *reinterpret_cast<const bf16x8*>(a1 + kk);
    bf16x8 bg0 = *reinterpret_cast<const bf16x8*>(b0 + kk);
    bf16x8 bg1 = *reinterpret_cast<const bf16x8*>(b1 + kk);
    acc[0][0] = __builtin_amdgcn_mfma_f32_16x16x32_bf16(af0, bg0, acc[0][0], 0, 0, 0);
    acc[0][1] = __builtin_amdgcn_mfma_f32_16x16x32_bf16(af0, bg1, acc[0][1], 0, 0, 0);
    acc[1][0] = __builtin_amdgcn_mfma_f32_16x16x32_bf16(af1, bg0, acc[1][0], 0, 0, 0);
    acc[1][1] = __builtin_amdgcn_mfma_f32_16x16x32_bf16(af1, bg1, acc[1][1], 0, 0, 0);
  }
}

// ---------------- proj_q: qh [B,H,S,D], 4-wave blocks (64x64 tile) ----------
__global__ __launch_bounds__(256) void proj_q_kernel(
    const unsigned short* __restrict__ qb, const unsigned short* __restrict__ Wq,
    unsigned short* __restrict__ qh) {
  const int w = threadIdx.x >> 6;
  const int row0 = blockIdx.y * 64 + (w >> 1) * 32;
  const int col0 = blockIdx.x * 64 + (w & 1) * 32;
  f32x4 acc[2][2] = {};
  mfma_tile_32x32(qb, kE, Wq, kE, row0, col0, kE, acc);
  const int lane = threadIdx.x & 63;
#pragma unroll
  for (int ri = 0; ri < 2; ++ri)
#pragma unroll
    for (int ci = 0; ci < 2; ++ci)
#pragma unroll
      for (int r = 0; r < 4; ++r) {
        int i = row0 + 16 * ri + 4 * (lane >> 4) + r;  // b*512+s
        int j = col0 + 16 * ci + (lane & 15);          // h*64+d
        int b = i >> 9, s = i & 511, h = j >> 6, d = j & 63;
        qh[(((size_t)(b * kH + h) * kS) + s) * kD + d] = f2bf(acc[ri][ci][r]);
      }
}

// ---------------- mega: qp (BW-bound) + proj_k/proj_v (MFMA) co-resident ----
// flat%3==2 -> proj block (512 total: 256 k, 256 v), else qp block (1024).
__global__ __launch_bounds__(256) void mega_kernel(
    const float* __restrict__ p, const unsigned short* __restrict__ qh,
    unsigned short* __restrict__ qp,
    const unsigned short* __restrict__ kb, const unsigned short* __restrict__ vb,
    const unsigned short* __restrict__ Wk, const unsigned short* __restrict__ Wv,
    unsigned short* __restrict__ kh, unsigned short* __restrict__ vhT) {
  __shared__ float qsh[kH][kD];
  const int flat = blockIdx.x;
  const int mod = flat % 3;
  if (mod == 2) {
    // ---- k/v projection: 64x64 tile, 4 waves ----
    const int pidx = flat / 3;       // 0..511
    const int which = pidx >> 8;     // 0=k, 1=v
    const int tile = pidx & 255;
    const int w = threadIdx.x >> 6;
    const int row0 = (tile >> 4) * 64 + (w >> 1) * 32;
    const int col0 = (tile & 15) * 64 + (w & 1) * 32;
    const unsigned short* A = which ? vb : kb;
    const unsigned short* W = which ? Wv : Wk;
    f32x4 acc[2][2] = {};
    mfma_tile_32x32(A, kE, W, kE, row0, col0, kE, acc);
    const int lane = threadIdx.x & 63;
#pragma unroll
    for (int ri = 0; ri < 2; ++ri)
#pragma unroll
      for (int ci = 0; ci < 2; ++ci)
#pragma unroll
        for (int r = 0; r < 4; ++r) {
          int i = row0 + 16 * ri + 4 * (lane >> 4) + r;
          int j = col0 + 16 * ci + (lane & 15);
          int b = i >> 9, s = i & 511, h = j >> 6, d = j & 63;
          unsigned short val = f2bf(acc[ri][ci][r]);
          if (which)
            vhT[(((size_t)(b * kH + h) * kD) + d) * kS + s] = val;
          else
            kh[(((size_t)(b * kH + h) * kS) + s) * kD + d] = val;
        }
  } else {
    // ---- qp[b,h,s,f] = sum_e qh[b,h,s,e] * p[b,s,h,e,f] ----
    const int bs = (flat / 3) * 2 + mod;  // 0..1023
    const int b = bs >> 9, s = bs & 511;
    const int t = threadIdx.x;
    {
      int h = t >> 4, d4 = (t & 15) * 4;
      const unsigned short* qr =
          qh + (((size_t)(b * kH + h) * kS) + s) * kD + d4;
      ushort4 u = *reinterpret_cast<const ushort4*>(qr);
      qsh[h][d4 + 0] = bf2f(u.x);
      qsh[h][d4 + 1] = bf2f(u.y);
      qsh[h][d4 + 2] = bf2f(u.z);
      qsh[h][d4 + 3] = bf2f(u.w);
    }
    __syncthreads();
    const int h = t >> 4, fi = t & 15;
    const float4* p4 =
        reinterpret_cast<const float4*>(p + ((size_t)(bs * kH + h) << 12));
    float4 acc = {0.f, 0.f, 0.f, 0.f};
#pragma unroll 4
    for (int e = 0; e < kD; ++e) {
      float4 pv = p4[e * 16 + fi];
      float qv = qsh[h][e];
      acc.x += qv * pv.x;
      acc.y += qv * pv.y;
      acc.z += qv * pv.z;
      acc.w += qv * pv.w;
    }
    ushort4 o;
    o.x = f2bf(acc.x); o.y = f2bf(acc.y); o.z = f2bf(acc.z); o.w = f2bf(acc.w);
    *reinterpret_cast<ushort4*>(
        qp + (((size_t)(b * kH + h) * kS) + s) * kD + fi * 4) = o;
  }
}

// ---------------- fused scores -> softmax -> PV -------------------------------
__global__ __launch_bounds__(256) void attn_kernel(
    const unsigned short* __restrict__ qp,
    const unsigned short* __restrict__ kh,
    const unsigned short* __restrict__ vhT,
    unsigned short* __restrict__ att) {
  __shared__ float S[32 * kSP];  // ~67 KB
  const int bh = blockIdx.y;
  const int b = bh >> 4, h = bh & 15;
  const int bx = blockIdx.x;
  const int row0 = bx * 32;
  const int ncol = row0 + 32;
  const int w = threadIdx.x >> 6;
  const int lane = threadIdx.x & 63;
  const int g = lane >> 4, c = lane & 15;

  const unsigned short* Abase = qp + (size_t)bh * kS * kD;
  const unsigned short* Kbase = kh + (size_t)bh * kS * kD;

  bf16x8 qa[2][2];
#pragma unroll
  for (int ri = 0; ri < 2; ++ri)
#pragma unroll
    for (int kk = 0; kk < 2; ++kk)
      qa[ri][kk] = *reinterpret_cast<const bf16x8*>(
          Abase + (size_t)(row0 + 16 * ri + c) * kD + kk * 32 + g * 8);

  // ---- phase 1: scores ----
  for (int ct = w; ct <= bx; ct += 4) {
    const int col0 = ct * 32;
    const unsigned short* kr0 = Kbase + (size_t)(col0 + c) * kD + g * 8;
    bf16x8 kb00 = *reinterpret_cast<const bf16x8*>(kr0);
    bf16x8 kb01 = *reinterpret_cast<const bf16x8*>(kr0 + 32);
    bf16x8 kb10 = *reinterpret_cast<const bf16x8*>(kr0 + 16 * kD);
    bf16x8 kb11 = *reinterpret_cast<const bf16x8*>(kr0 + 16 * kD + 32);
    f32x4 sacc[2][2] = {};
    sacc[0][0] = __builtin_amdgcn_mfma_f32_16x16x32_bf16(qa[0][0], kb00, sacc[0][0], 0, 0, 0);
    sacc[0][0] = __builtin_amdgcn_mfma_f32_16x16x32_bf16(qa[0][1], kb01, sacc[0][0], 0, 0, 0);
    sacc[0][1] = __builtin_amdgcn_mfma_f32_16x16x32_bf16(qa[0][0], kb10, sacc[0][1], 0, 0, 0);
    sacc[0][1] = __builtin_amdgcn_mfma_f32_16x16x32_bf16(qa[0][1], kb11, sacc[0][1], 0, 0, 0);
    sacc[1][0] = __builtin_amdgcn_mfma_f32_16x16x32_bf16(qa[1][0], kb00, sacc[1][0], 0, 0, 0);
    sacc[1][0] = __builtin_amdgcn_mfma_f32_16x16x32_bf16(qa[1][1], kb01, sacc[1][0], 0, 0, 0);
    sacc[1][1] = __builtin_amdgcn_mfma_f32_16x16x32_bf16(qa[1][0], kb10, sacc[1][1], 0, 0, 0);
    sacc[1][1] = __builtin_amdgcn_mfma_f32_16x16x32_bf16(qa[1][1], kb11, sacc[1][1], 0, 0, 0);
#pragma unroll
    for (int ri = 0; ri < 2; ++ri)
#pragma unroll
      for (int ci = 0; ci < 2; ++ci)
#pragma unroll
        for (int r = 0; r < 4; ++r) {
          int il = 16 * ri + 4 * g + r;
          int jg = col0 + 16 * ci + c;
          float val = sacc[ri][ci][r] * 0.125f;
          if (jg > row0 + il) val = -1e9f;
          S[il * kSP + jg] = val;
        }
  }
  __syncthreads();

  // ---- phase 2: softmax, rows w*8 .. w*8+7 ----
#pragma unroll
  for (int rr = 0; rr < 8; ++rr) {
    const int i = w * 8 + rr;
    float v[8];
    float m = -1e30f;
#pragma unroll
    for (int ii = 0; ii < 8; ++ii) {
      int j = lane + 64 * ii;
      v[ii] = (j < ncol) ? S[i * kSP + j] : -1e30f;
      m = fmaxf(m, v[ii]);
    }
#pragma unroll
    for (int off = 32; off; off >>= 1) m = fmaxf(m, __shfl_xor(m, off));
    float e[8], sum = 0.f;
#pragma unroll
    for (int ii = 0; ii < 8; ++ii) {
      e[ii] = __expf(v[ii] - m);
      sum += e[ii];
    }
#pragma unroll
    for (int off = 32; off; off >>= 1) sum += __shfl_xor(sum, off);
    const float inv = 1.0f / sum;
#pragma unroll
    for (int ii = 0; ii < 8; ++ii) S[i * kSP + lane + 64 * ii] = e[ii] * inv;
  }
  __syncthreads();

  // ---- phase 3: PV, wave w handles d in [16w, 16w+16) ----
  const int d0 = w * 16;
  const unsigned short* Vbase = vhT + (size_t)(bh * kD + d0 + c) * kS;
  f32x4 oacc[2] = {};
  const int nk = bx + 1;
  for (int ks = 0; ks < nk; ++ks) {
    const int kb = ks * 32;
    bf16x8 vfrag = *reinterpret_cast<const bf16x8*>(Vbase + kb + g * 8);
#pragma unroll
    for (int ri = 0; ri < 2; ++ri) {
      const float* sp = &S[(16 * ri + c) * kSP + kb + g * 8];
      float4 x0 = *reinterpret_cast<const float4*>(sp);
      float4 x1 = *reinterpret_cast<const float4*>(sp + 4);
      bf16x8 pa;
      pa[0] = (short)f2bf(x0.x); pa[1] = (short)f2bf(x0.y);
      pa[2] = (short)f2bf(x0.z); pa[3] = (short)f2bf(x0.w);
      pa[4] = (short)f2bf(x1.x); pa[5] = (short)f2bf(x1.y);
      pa[6] = (short)f2bf(x1.z); pa[7] = (short)f2bf(x1.w);
      oacc[ri] = __builtin_amdgcn_mfma_f32_16x16x32_bf16(pa, vfrag, oacc[ri], 0, 0, 0);
    }
  }
#pragma unroll
  for (int ri = 0; ri < 2; ++ri)
#pragma unroll
    for (int r = 0; r < 4; ++r) {
      int s = row0 + 16 * ri + 4 * g + r;
      int d = d0 + c;
      att[((size_t)(b * kS + s) * kE) + h * kD + d] = f2bf(oacc[ri][r]);
    }
}

// ---------------- out = att @ Wo^T (f32 output), 4-wave blocks ---------------
__global__ __launch_bounds__(256) void out_kernel(
    const unsigned short* __restrict__ att, const unsigned short* __restrict__ Wo,
    float* __restrict__ out) {
  const int w = threadIdx.x >> 6;
  const int row0 = blockIdx.y * 64 + (w >> 1) * 32;
  const int col0 = blockIdx.x * 64 + (w & 1) * 32;
  f32x4 acc[2][2] = {};
  mfma_tile_32x32(att, kE, Wo, kE, row0, col0, kE, acc);
  const int lane = threadIdx.x & 63;
#pragma unroll
  for (int ri = 0; ri < 2; ++ri)
#pragma unroll
    for (int ci = 0; ci < 2; ++ci)
#pragma unroll
      for (int r = 0; r < 4; ++r) {
        int i = row0 + 16 * ri + 4 * (lane >> 4) + r;
        int j = col0 + 16 * ci + (lane & 15);
        out[(size_t)i * kE + j] = acc[ri][ci][r];
      }
}

}  // namespace

extern "C" void kernel_launch(void* const* d_in, const int* in_sizes, int n_in,
                              void* d_out, int out_size, void* d_ws,
                              size_t ws_size, hipStream_t stream) {
  const float* q = (const float*)d_in[0];
  const float* k = (const float*)d_in[1];
  const float* v = (const float*)d_in[2];
  const float* p = (const float*)d_in[3];
  const float* Wq = (const float*)d_in[5];
  const float* Wk = (const float*)d_in[6];
  const float* Wv = (const float*)d_in[7];
  const float* Wo = (const float*)d_in[8];
  float* out = (float*)d_out;

  char* ws = (char*)d_ws;
  size_t off = 0;
  auto alloc = [&](size_t bytes) {
    void* ptr = ws + off;
    off += (bytes + 255) & ~(size_t)255;
    return ptr;
  };
  const size_t nME = (size_t)kM * kE;  // 1,048,576
  // NOTE: these 7 must stay consecutive 2MB regions (cvt7 indexes off qb).
  unsigned short* qb = (unsigned short*)alloc(nME * 2);
  unsigned short* kb = (unsigned short*)alloc(nME * 2);
  unsigned short* vb = (unsigned short*)alloc(nME * 2);
  unsigned short* Wqb = (unsigned short*)alloc(nME * 2);
  unsigned short* Wkb = (unsigned short*)alloc(nME * 2);
  unsigned short* Wvb = (unsigned short*)alloc(nME * 2);
  unsigned short* Wob = (unsigned short*)alloc(nME * 2);
  unsigned short* qhB = (unsigned short*)alloc(nME * 2);
  unsigned short* khB = (unsigned short*)alloc(nME * 2);
  unsigned short* vhTB = (unsigned short*)alloc(nME * 2);
  unsigned short* qpB = (unsigned short*)alloc(nME * 2);
  unsigned short* attB = (unsigned short*)alloc(nME * 2);

  cvt7_kernel<<<dim3(kM * kE / (256 * 4), 7), 256, 0, stream>>>(
      q, k, v, Wq, Wk, Wv, Wo, qb);

  proj_q_kernel<<<dim3(kE / 64, kM / 64), 256, 0, stream>>>(qb, Wqb, qhB);

  mega_kernel<<<1536, 256, 0, stream>>>(p, qhB, qpB, kb, vb, Wkb, Wvb, khB,
                                        vhTB);

  attn_kernel<<<dim3(kS / 32, kBH), 256, 0, stream>>>(qpB, khB, vhTB, attB);

  out_kernel<<<dim3(kE / 64, kM / 64), 256, 0, stream>>>(attB, Wob, out);
}